// Round 2
// baseline (635.015 us; speedup 1.0000x reference)
//
#include <hip/hip_runtime.h>
#include <stdint.h>

typedef unsigned short ushort_t;
typedef float  f32x4  __attribute__((ext_vector_type(4)));
typedef short  short8 __attribute__((ext_vector_type(8)));
typedef short  short4v __attribute__((ext_vector_type(4)));

#define SCALE 0.125f   // 1/sqrt(64)

__device__ __forceinline__ ushort_t f2bf(float f) {
  unsigned u = __builtin_bit_cast(unsigned, f);
  unsigned r = (u + 0x7fffu + ((u >> 16) & 1u)) >> 16;
  return (ushort_t)r;
}

// ---------------------------------------------------------------------------
// (B,C,L) f32 -> (B,L,C) bf16 transpose+convert. 64x64 tiles, 256 threads.
__global__ __launch_bounds__(256) void transpose_cvt(const float* __restrict__ in,
                                                     ushort_t* __restrict__ out) {
  __shared__ float tile[64][65];
  int b  = blockIdx.z;
  int c0 = blockIdx.x * 64, l0 = blockIdx.y * 64;
  int col = threadIdx.x & 63;
  int row4 = threadIdx.x >> 6;
  const float* p = in + ((size_t)b * 1024 + c0) * 1024 + l0;
#pragma unroll
  for (int i = 0; i < 16; ++i) {
    int r = row4 * 16 + i;
    tile[r][col] = p[(size_t)r * 1024 + col];
  }
  __syncthreads();
  ushort_t* q = out + ((size_t)b * 1024 + l0) * 1024 + c0;
#pragma unroll
  for (int i = 0; i < 16; ++i) {
    int r = row4 * 16 + i;
    q[(size_t)r * 1024 + col] = f2bf(tile[col][r]);
  }
}

// flat f32 -> bf16 (for the 1024x1024 weights); grid*256*4 == n exactly
__global__ __launch_bounds__(256) void cvt_bf16(const float* __restrict__ in,
                                                ushort_t* __restrict__ out) {
  int i = blockIdx.x * 256 + threadIdx.x;
  f32x4 v = *reinterpret_cast<const f32x4*>(in + (size_t)i * 4);
  short4v pk;
#pragma unroll
  for (int j = 0; j < 4; ++j) pk[j] = (short)f2bf(v[j]);
  *reinterpret_cast<short4v*>(out + (size_t)i * 4) = pk;
}

// ---------------------------------------------------------------------------
// C[o,l] = sum_c A[o,c]*BT[l,c] + bias[o], all 1024^3 per batch, bf16 in/out,
// f32 accum. 128x128 tile, BK=32, 4 waves each 64x64 (4x4 frags 16x16x32).
// OUT_T=true: write [bh][t][d] (bh = b*16 + o/64, d = o&63) as packed 4xbf16.
// OUT_T=false: write [b*1024 + o][l] row-major bf16.
template <bool OUT_T>
__global__ __launch_bounds__(256) void gemm_bt(const ushort_t* __restrict__ A,
                                               const ushort_t* __restrict__ BT,
                                               const float* __restrict__ bias,
                                               ushort_t* __restrict__ outp) {
  __shared__ ushort_t As[128 * 32];
  __shared__ ushort_t Bs[128 * 32];
  int b = blockIdx.z;
  int Mbase = blockIdx.y * 128, Nbase = blockIdx.x * 128;
  int tid = threadIdx.x;
  int lane = tid & 63, wave = tid >> 6;
  int wr = wave >> 1, wc = wave & 1;
  int lo = lane & 15, hi = lane >> 4;
  const ushort_t* Bb = BT + ((size_t)b << 20);

  f32x4 acc[4][4] = {};

  for (int kt = 0; kt < 1024; kt += 32) {
#pragma unroll
    for (int it = 0; it < 2; ++it) {
      int cch = tid + it * 256;
      int r = cch >> 2, p = cch & 3;
      *reinterpret_cast<short8*>(&As[r * 32 + p * 8]) =
          *reinterpret_cast<const short8*>(A + (size_t)(Mbase + r) * 1024 + kt + p * 8);
      *reinterpret_cast<short8*>(&Bs[r * 32 + p * 8]) =
          *reinterpret_cast<const short8*>(Bb + (size_t)(Nbase + r) * 1024 + kt + p * 8);
    }
    __syncthreads();
    short8 af[4], bf[4];
#pragma unroll
    for (int m = 0; m < 4; ++m)
      af[m] = *reinterpret_cast<const short8*>(&As[(wr * 64 + m * 16 + lo) * 32 + hi * 8]);
#pragma unroll
    for (int n = 0; n < 4; ++n)
      bf[n] = *reinterpret_cast<const short8*>(&Bs[(wc * 64 + n * 16 + lo) * 32 + hi * 8]);
#pragma unroll
    for (int m = 0; m < 4; ++m)
#pragma unroll
      for (int n = 0; n < 4; ++n)
        acc[m][n] = __builtin_amdgcn_mfma_f32_16x16x32_bf16(af[m], bf[n], acc[m][n], 0, 0, 0);
    __syncthreads();
  }

#pragma unroll
  for (int m = 0; m < 4; ++m) {
    int o0 = Mbase + wr * 64 + m * 16 + hi * 4;
#pragma unroll
    for (int n = 0; n < 4; ++n) {
      int col = Nbase + wc * 64 + n * 16 + lo;
      if (OUT_T) {
        short4v pk;
#pragma unroll
        for (int j = 0; j < 4; ++j) pk[j] = (short)f2bf(acc[m][n][j] + bias[o0 + j]);
        *reinterpret_cast<short4v*>(outp + ((size_t)b << 20) + ((size_t)(o0 >> 6) << 16) +
                                    (size_t)col * 64 + (o0 & 63)) = pk;
      } else {
#pragma unroll
        for (int j = 0; j < 4; ++j)
          outp[((size_t)b << 20) + (size_t)(o0 + j) * 1024 + col] =
              f2bf(acc[m][n][j] + bias[o0 + j]);
      }
    }
  }
}

// ---------------------------------------------------------------------------
// Pass 1: invZ[bh][s] = 1 / sum_t exp(SCALE * q_t . k_s). No max-subtraction
// (scores ~N(0,1), max ~6, exp fits f32 easily).
// Computes S^T tiles: A = khT rows (16 s per wave), B = qhT (16 t per step).
__global__ __launch_bounds__(256) void attn_pass1(const ushort_t* __restrict__ qhT,
                                                  const ushort_t* __restrict__ khT,
                                                  float* __restrict__ invZ) {
  int bh = blockIdx.y;
  int lane = threadIdx.x & 63, wave = threadIdx.x >> 6;
  int lo = lane & 15, hi = lane >> 4;
  int s_base = blockIdx.x * 64 + wave * 16;
  const ushort_t* kb = khT + ((size_t)bh << 16);
  const ushort_t* qb = qhT + ((size_t)bh << 16);

  short8 a0 = *reinterpret_cast<const short8*>(kb + (size_t)(s_base + lo) * 64 + hi * 8);
  short8 a1 = *reinterpret_cast<const short8*>(kb + (size_t)(s_base + lo) * 64 + 32 + hi * 8);

  float zs[4] = {0.f, 0.f, 0.f, 0.f};
  for (int t0 = 0; t0 < 1024; t0 += 16) {
    short8 b0 = *reinterpret_cast<const short8*>(qb + (size_t)(t0 + lo) * 64 + hi * 8);
    short8 b1 = *reinterpret_cast<const short8*>(qb + (size_t)(t0 + lo) * 64 + 32 + hi * 8);
    f32x4 d = {0.f, 0.f, 0.f, 0.f};
    d = __builtin_amdgcn_mfma_f32_16x16x32_bf16(a0, b0, d, 0, 0, 0);
    d = __builtin_amdgcn_mfma_f32_16x16x32_bf16(a1, b1, d, 0, 0, 0);
#pragma unroll
    for (int j = 0; j < 4; ++j) zs[j] += __expf(d[j] * SCALE);
  }
#pragma unroll
  for (int j = 0; j < 4; ++j) {
    float v = zs[j];
    v += __shfl_xor(v, 1);
    v += __shfl_xor(v, 2);
    v += __shfl_xor(v, 4);
    v += __shfl_xor(v, 8);
    if (lo == 0) invZ[bh * 1024 + s_base + hi * 4 + j] = 1.0f / v;
  }
}

// ---------------------------------------------------------------------------
// Pass 2: out[bh][d][t] = sum_s (exp(SCALE*S[t,s]) * invZ[s]) * vh[d][s].
// Per wave: 16 t columns. S^T tiles via mfma(K,Q); P^T -> LDS -> PV B-frag;
// PV: A = vh[d][s] (s-contiguous), K=32 per step.
__global__ __launch_bounds__(256) void attn_pass2(const ushort_t* __restrict__ qhT,
                                                  const ushort_t* __restrict__ khT,
                                                  const ushort_t* __restrict__ vh,
                                                  const float* __restrict__ invZ,
                                                  float* __restrict__ out) {
  __shared__ ushort_t Pt[4][16][32];
  int bh = blockIdx.y;
  int lane = threadIdx.x & 63, wave = threadIdx.x >> 6;
  int lo = lane & 15, hi = lane >> 4;
  int t0 = blockIdx.x * 64 + wave * 16;
  const ushort_t* qb = qhT + ((size_t)bh << 16);
  const ushort_t* kb = khT + ((size_t)bh << 16);
  const ushort_t* vb = vh + ((size_t)bh << 16);
  const float* izb = invZ + bh * 1024;

  short8 bq0 = *reinterpret_cast<const short8*>(qb + (size_t)(t0 + lo) * 64 + hi * 8);
  short8 bq1 = *reinterpret_cast<const short8*>(qb + (size_t)(t0 + lo) * 64 + 32 + hi * 8);

  f32x4 facc[4] = {};

  for (int s0 = 0; s0 < 1024; s0 += 32) {
#pragma unroll
    for (int st = 0; st < 2; ++st) {
      int sb = s0 + st * 16;
      short8 ak0 = *reinterpret_cast<const short8*>(kb + (size_t)(sb + lo) * 64 + hi * 8);
      short8 ak1 = *reinterpret_cast<const short8*>(kb + (size_t)(sb + lo) * 64 + 32 + hi * 8);
      f32x4 d = {0.f, 0.f, 0.f, 0.f};
      d = __builtin_amdgcn_mfma_f32_16x16x32_bf16(ak0, bq0, d, 0, 0, 0);
      d = __builtin_amdgcn_mfma_f32_16x16x32_bf16(ak1, bq1, d, 0, 0, 0);
      short4v pk;
#pragma unroll
      for (int j = 0; j < 4; ++j)
        pk[j] = (short)f2bf(__expf(d[j] * SCALE) * izb[sb + hi * 4 + j]);
      *reinterpret_cast<short4v*>(&Pt[wave][lo][st * 16 + hi * 4]) = pk;
    }
    asm volatile("s_waitcnt lgkmcnt(0)" ::: "memory");
    __builtin_amdgcn_sched_barrier(0);
    short8 bp = *reinterpret_cast<const short8*>(&Pt[wave][lo][hi * 8]);
#pragma unroll
    for (int m = 0; m < 4; ++m) {
      short8 av = *reinterpret_cast<const short8*>(vb + (size_t)(m * 16 + lo) * 1024 + s0 + hi * 8);
      facc[m] = __builtin_amdgcn_mfma_f32_16x16x32_bf16(av, bp, facc[m], 0, 0, 0);
    }
  }

  float* ob = out + ((size_t)bh << 16);
#pragma unroll
  for (int m = 0; m < 4; ++m)
#pragma unroll
    for (int j = 0; j < 4; ++j)
      ob[(size_t)(m * 16 + hi * 4 + j) * 1024 + t0 + lo] = facc[m][j];
}

// ---------------------------------------------------------------------------
extern "C" void kernel_launch(void* const* d_in, const int* in_sizes, int n_in,
                              void* d_out, int out_size, void* d_ws, size_t ws_size,
                              hipStream_t stream) {
  const float* q  = (const float*)d_in[0];
  const float* k  = (const float*)d_in[1];
  const float* v  = (const float*)d_in[2];
  const float* Wq = (const float*)d_in[3];
  const float* bq = (const float*)d_in[4];
  const float* Wk = (const float*)d_in[5];
  const float* bk = (const float*)d_in[6];
  const float* Wv = (const float*)d_in[7];
  const float* bv = (const float*)d_in[8];
  float* out = (float*)d_out;
  char* ws = (char*)d_ws;
  const size_t MB = 1u << 20;

  // workspace plan (70.5 MB peak, with region reuse):
  ushort_t* xTq = (ushort_t*)(ws);            // 16MB; reused as khT
  ushort_t* xTk = (ushort_t*)(ws + 16 * MB);  // 16MB; reused as vh
  ushort_t* xTv = (ushort_t*)(ws + 32 * MB);  // 16MB
  ushort_t* Wqb = (ushort_t*)(ws + 48 * MB);  // 2MB
  ushort_t* Wkb = (ushort_t*)(ws + 50 * MB);  // 2MB
  ushort_t* Wvb = (ushort_t*)(ws + 52 * MB);  // 2MB
  ushort_t* qhT = (ushort_t*)(ws + 54 * MB);  // 16MB
  ushort_t* khT = xTq;                        // written after xTq is dead
  ushort_t* vhb = xTk;                        // written after xTk is dead
  float*    invZ = (float*)(ws + 70 * MB);    // 0.5MB

  dim3 tb(256);
  transpose_cvt<<<dim3(16, 16, 8), tb, 0, stream>>>(q, xTq);
  transpose_cvt<<<dim3(16, 16, 8), tb, 0, stream>>>(k, xTk);
  transpose_cvt<<<dim3(16, 16, 8), tb, 0, stream>>>(v, xTv);
  cvt_bf16<<<dim3(1024), tb, 0, stream>>>(Wq, Wqb);
  cvt_bf16<<<dim3(1024), tb, 0, stream>>>(Wk, Wkb);
  cvt_bf16<<<dim3(1024), tb, 0, stream>>>(Wv, Wvb);
  gemm_bt<true ><<<dim3(8, 8, 8), tb, 0, stream>>>(Wqb, xTq, bq, qhT);
  gemm_bt<true ><<<dim3(8, 8, 8), tb, 0, stream>>>(Wkb, xTk, bk, khT);
  gemm_bt<false><<<dim3(8, 8, 8), tb, 0, stream>>>(Wvb, xTv, bv, vhb);
  attn_pass1<<<dim3(16, 128), tb, 0, stream>>>(qhT, khT, invZ);
  attn_pass2<<<dim3(16, 128), tb, 0, stream>>>(qhT, khT, vhb, invZ, out);
}

// Round 3
// 625.223 us; speedup vs baseline: 1.0157x; 1.0157x over previous
//
#include <hip/hip_runtime.h>
#include <stdint.h>

typedef unsigned short ushort_t;
typedef float  f32x4  __attribute__((ext_vector_type(4)));
typedef short  short8 __attribute__((ext_vector_type(8)));
typedef short  short4v __attribute__((ext_vector_type(4)));

// softmax base-2: scores pre-scaled by (1/8)*log2(e) folded into Q projection.
#define QSCALE 0.18033688011112043f

__device__ __forceinline__ ushort_t f2bf(float f) {
  unsigned u = __builtin_bit_cast(unsigned, f);
  unsigned r = (u + 0x7fffu + ((u >> 16) & 1u)) >> 16;
  return (ushort_t)r;
}
__device__ __forceinline__ float bf2f(ushort_t u) {
  unsigned x = (unsigned)u << 16;
  return __builtin_bit_cast(float, x);
}

typedef const __attribute__((address_space(1))) unsigned int* gas_t;
typedef __attribute__((address_space(3))) unsigned int* las_t;
__device__ __forceinline__ void gload16(const void* g, void* l) {
  __builtin_amdgcn_global_load_lds((gas_t)g, (las_t)l, 16, 0, 0);
}

// ---------------------------------------------------------------------------
// (B,C,L) f32 -> (B,L,C) bf16 transpose+convert. 64x64 tiles, 256 threads.
__global__ __launch_bounds__(256) void transpose_cvt(const float* __restrict__ in,
                                                     ushort_t* __restrict__ out) {
  __shared__ float tile[64][65];
  int b  = blockIdx.z;
  int c0 = blockIdx.x * 64, l0 = blockIdx.y * 64;
  int col = threadIdx.x & 63;
  int row4 = threadIdx.x >> 6;
  const float* p = in + ((size_t)b * 1024 + c0) * 1024 + l0;
#pragma unroll
  for (int i = 0; i < 16; ++i) {
    int r = row4 * 16 + i;
    tile[r][col] = p[(size_t)r * 1024 + col];
  }
  __syncthreads();
  ushort_t* q = out + ((size_t)b * 1024 + l0) * 1024 + c0;
#pragma unroll
  for (int i = 0; i < 16; ++i) {
    int r = row4 * 16 + i;
    q[(size_t)r * 1024 + col] = f2bf(tile[col][r]);
  }
}

// flat f32 -> bf16 with scale; grid*256*4 == n exactly
__global__ __launch_bounds__(256) void cvt_bf16(const float* __restrict__ in,
                                                ushort_t* __restrict__ out, float sc) {
  int i = blockIdx.x * 256 + threadIdx.x;
  f32x4 v = *reinterpret_cast<const f32x4*>(in + (size_t)i * 4);
  short4v pk;
#pragma unroll
  for (int j = 0; j < 4; ++j) pk[j] = (short)f2bf(v[j] * sc);
  *reinterpret_cast<short4v*>(out + (size_t)i * 4) = pk;
}

// ---------------------------------------------------------------------------
// C[o,l] = sum_c A[o,c]*BT[l,c] + bias[o]*bs. 128x128 tile, BK=32,
// global_load_lds width-16 staging, 4 waves each 64x64 (4x4 frags 16x16x32).
template <bool OUT_T>
__global__ __launch_bounds__(256) void gemm_bt(const ushort_t* __restrict__ A,
                                               const ushort_t* __restrict__ BT,
                                               const float* __restrict__ bias,
                                               float bs,
                                               ushort_t* __restrict__ outp) {
  __shared__ ushort_t As[128 * 32];
  __shared__ ushort_t Bs[128 * 32];
  int b = blockIdx.z;
  int Mbase = blockIdx.y * 128, Nbase = blockIdx.x * 128;
  int tid = threadIdx.x;
  int lane = tid & 63, wave = tid >> 6;
  int wr = wave >> 1, wc = wave & 1;
  int lo = lane & 15, hi = lane >> 4;
  const ushort_t* Bb = BT + ((size_t)b << 20);

  f32x4 acc[4][4] = {};

  for (int kt = 0; kt < 1024; kt += 32) {
#pragma unroll
    for (int it = 0; it < 2; ++it) {
      int cch = tid + it * 256;
      int r = cch >> 2, p = cch & 3;
      gload16(A + (size_t)(Mbase + r) * 1024 + kt + p * 8, &As[it * 2048 + wave * 512]);
      gload16(Bb + (size_t)(Nbase + r) * 1024 + kt + p * 8, &Bs[it * 2048 + wave * 512]);
    }
    __syncthreads();
    short8 af[4], bf[4];
#pragma unroll
    for (int m = 0; m < 4; ++m)
      af[m] = *reinterpret_cast<const short8*>(&As[(wr * 64 + m * 16 + lo) * 32 + hi * 8]);
#pragma unroll
    for (int n = 0; n < 4; ++n)
      bf[n] = *reinterpret_cast<const short8*>(&Bs[(wc * 64 + n * 16 + lo) * 32 + hi * 8]);
#pragma unroll
    for (int m = 0; m < 4; ++m)
#pragma unroll
      for (int n = 0; n < 4; ++n)
        acc[m][n] = __builtin_amdgcn_mfma_f32_16x16x32_bf16(af[m], bf[n], acc[m][n], 0, 0, 0);
    __syncthreads();
  }

#pragma unroll
  for (int m = 0; m < 4; ++m) {
    int o0 = Mbase + wr * 64 + m * 16 + hi * 4;
#pragma unroll
    for (int n = 0; n < 4; ++n) {
      int col = Nbase + wc * 64 + n * 16 + lo;
      if (OUT_T) {
        short4v pk;
#pragma unroll
        for (int j = 0; j < 4; ++j) pk[j] = (short)f2bf(acc[m][n][j] + bias[o0 + j] * bs);
        *reinterpret_cast<short4v*>(outp + ((size_t)b << 20) + ((size_t)(o0 >> 6) << 16) +
                                    (size_t)col * 64 + (o0 & 63)) = pk;
      } else {
#pragma unroll
        for (int j = 0; j < 4; ++j)
          outp[((size_t)b << 20) + (size_t)(o0 + j) * 1024 + col] =
              f2bf(acc[m][n][j] + bias[o0 + j] * bs);
      }
    }
  }
}

// ---------------------------------------------------------------------------
// attn_p1: P[bh][t][s] = 2^(qs.ks) (bf16, unnormalized), invZ[bh][s] = 1/sum_t.
// Block: 128 s (fixed, K-frags in regs), loop t in steps of 128. 4 waves 2x2.
__global__ __launch_bounds__(256) void attn_p1(const ushort_t* __restrict__ qhT,
                                               const ushort_t* __restrict__ khT,
                                               ushort_t* __restrict__ P,
                                               float* __restrict__ invZ) {
  __shared__ float zbuf[2][2][64];
  int bid = blockIdx.y * 8 + blockIdx.x;
  int logical = (bid & 7) * 128 + (bid >> 3);   // XCD-bijective swizzle (1024=8*128)
  int sblk = logical & 7, bh = logical >> 3;
  int tid = threadIdx.x;
  int lane = tid & 63, wave = tid >> 6;
  int wr = wave >> 1, wc = wave & 1;
  int lo = lane & 15, hi = lane >> 4;
  const ushort_t* kb = khT + ((size_t)bh << 16);
  const ushort_t* qb = qhT + ((size_t)bh << 16);
  ushort_t* Pb = P + ((size_t)bh << 20);

  int sbase = sblk * 128 + wr * 64;
  short8 af[4][2];
#pragma unroll
  for (int m = 0; m < 4; ++m)
#pragma unroll
    for (int kk = 0; kk < 2; ++kk)
      af[m][kk] = *reinterpret_cast<const short8*>(
          kb + (size_t)(sbase + m * 16 + lo) * 64 + kk * 32 + hi * 8);

  float zp[4][4] = {};

  for (int t0 = 0; t0 < 1024; t0 += 128) {
    int tbase = t0 + wc * 64;
    short8 bf[4][2];
#pragma unroll
    for (int n = 0; n < 4; ++n)
#pragma unroll
      for (int kk = 0; kk < 2; ++kk)
        bf[n][kk] = *reinterpret_cast<const short8*>(
            qb + (size_t)(tbase + n * 16 + lo) * 64 + kk * 32 + hi * 8);
#pragma unroll
    for (int m = 0; m < 4; ++m) {
      f32x4 d[4];
#pragma unroll
      for (int n = 0; n < 4; ++n) {
        f32x4 dd = {0.f, 0.f, 0.f, 0.f};
        dd = __builtin_amdgcn_mfma_f32_16x16x32_bf16(af[m][0], bf[n][0], dd, 0, 0, 0);
        dd = __builtin_amdgcn_mfma_f32_16x16x32_bf16(af[m][1], bf[n][1], dd, 0, 0, 0);
        d[n] = dd;
      }
#pragma unroll
      for (int n = 0; n < 4; ++n) {
        short4v pk;
#pragma unroll
        for (int j = 0; j < 4; ++j) {
          float p = exp2f(d[n][j]);
          zp[m][j] += p;
          pk[j] = (short)f2bf(p);
        }
        *reinterpret_cast<short4v*>(
            Pb + (size_t)(tbase + n * 16 + lo) * 1024 + sbase + m * 16 + hi * 4) = pk;
      }
    }
  }
#pragma unroll
  for (int m = 0; m < 4; ++m)
#pragma unroll
    for (int j = 0; j < 4; ++j) {
      float v = zp[m][j];
      v += __shfl_xor(v, 1);
      v += __shfl_xor(v, 2);
      v += __shfl_xor(v, 4);
      v += __shfl_xor(v, 8);
      if (lo == 0) zbuf[wc][wr][m * 16 + hi * 4 + j] = v;
    }
  __syncthreads();
  if (tid < 128) {
    float z = zbuf[0][tid >> 6][tid & 63] + zbuf[1][tid >> 6][tid & 63];
    invZ[bh * 1024 + sblk * 128 + tid] = 1.0f / z;
  }
}

// ---------------------------------------------------------------------------
// vh[bh][d][s] *= invZ[bh][s], in place. grid (32, 128).
__global__ __launch_bounds__(256) void vscale(ushort_t* __restrict__ vh,
                                              const float* __restrict__ invZ) {
  int bh = blockIdx.y;
  int idx = (blockIdx.x * 256 + threadIdx.x) * 8;
  int s = idx & 1023;
  ushort_t* p = vh + ((size_t)bh << 16) + idx;
  const float* iz = invZ + bh * 1024 + s;
  short8 v = *reinterpret_cast<const short8*>(p);
  short8 o;
#pragma unroll
  for (int j = 0; j < 8; ++j) o[j] = (short)f2bf(bf2f((ushort_t)v[j]) * iz[j]);
  *reinterpret_cast<short8*>(p) = o;
}

// ---------------------------------------------------------------------------
// gemm_pv: out[bh][d][t] = sum_s Vs[bh][d][s] * P[bh][t][s]. f32 out to d_out.
// 64d x 128t tile, 4 waves (each 64x32), global_load_lds staging.
__global__ __launch_bounds__(256) void gemm_pv(const ushort_t* __restrict__ Vs,
                                               const ushort_t* __restrict__ P,
                                               float* __restrict__ out) {
  __shared__ ushort_t As[64 * 32];
  __shared__ ushort_t Bs[128 * 32];
  int bid = blockIdx.y * 8 + blockIdx.x;
  int logical = (bid & 7) * 128 + (bid >> 3);   // XCD-bijective swizzle
  int tblk = logical & 7, bh = logical >> 3;
  int Nbase = tblk * 128;
  int tid = threadIdx.x;
  int lane = tid & 63, wave = tid >> 6;
  int lo = lane & 15, hi = lane >> 4;
  const ushort_t* Ab = Vs + ((size_t)bh << 16);
  const ushort_t* Bb = P + ((size_t)bh << 20) + (size_t)Nbase * 1024;

  f32x4 acc[4][2] = {};

  for (int kt = 0; kt < 1024; kt += 32) {
    {
      int r = tid >> 2, p = tid & 3;
      gload16(Ab + (size_t)r * 1024 + kt + p * 8, &As[wave * 512]);
    }
#pragma unroll
    for (int it = 0; it < 2; ++it) {
      int cch = tid + it * 256;
      int r = cch >> 2, p = cch & 3;
      gload16(Bb + (size_t)r * 1024 + kt + p * 8, &Bs[it * 2048 + wave * 512]);
    }
    __syncthreads();
    short8 a_[4], b_[2];
#pragma unroll
    for (int m = 0; m < 4; ++m)
      a_[m] = *reinterpret_cast<const short8*>(&As[(m * 16 + lo) * 32 + hi * 8]);
#pragma unroll
    for (int n = 0; n < 2; ++n)
      b_[n] = *reinterpret_cast<const short8*>(&Bs[(wave * 32 + n * 16 + lo) * 32 + hi * 8]);
#pragma unroll
    for (int m = 0; m < 4; ++m)
#pragma unroll
      for (int n = 0; n < 2; ++n)
        acc[m][n] = __builtin_amdgcn_mfma_f32_16x16x32_bf16(a_[m], b_[n], acc[m][n], 0, 0, 0);
    __syncthreads();
  }
  float* ob = out + ((size_t)bh << 16);
#pragma unroll
  for (int m = 0; m < 4; ++m)
#pragma unroll
    for (int n = 0; n < 2; ++n)
#pragma unroll
      for (int j = 0; j < 4; ++j)
        ob[(size_t)(m * 16 + hi * 4 + j) * 1024 + Nbase + wave * 32 + n * 16 + lo] =
            acc[m][n][j];
}

// ---------------------------------------------------------------------------
// Fallback path (small ws): original fused pass1/pass2, exp2 (Q pre-scaled).
__global__ __launch_bounds__(256) void attn_pass1(const ushort_t* __restrict__ qhT,
                                                  const ushort_t* __restrict__ khT,
                                                  float* __restrict__ invZ) {
  int bh = blockIdx.y;
  int lane = threadIdx.x & 63, wave = threadIdx.x >> 6;
  int lo = lane & 15, hi = lane >> 4;
  int s_base = blockIdx.x * 64 + wave * 16;
  const ushort_t* kb = khT + ((size_t)bh << 16);
  const ushort_t* qb = qhT + ((size_t)bh << 16);

  short8 a0 = *reinterpret_cast<const short8*>(kb + (size_t)(s_base + lo) * 64 + hi * 8);
  short8 a1 = *reinterpret_cast<const short8*>(kb + (size_t)(s_base + lo) * 64 + 32 + hi * 8);

  float zs[4] = {0.f, 0.f, 0.f, 0.f};
  for (int t0 = 0; t0 < 1024; t0 += 16) {
    short8 b0 = *reinterpret_cast<const short8*>(qb + (size_t)(t0 + lo) * 64 + hi * 8);
    short8 b1 = *reinterpret_cast<const short8*>(qb + (size_t)(t0 + lo) * 64 + 32 + hi * 8);
    f32x4 d = {0.f, 0.f, 0.f, 0.f};
    d = __builtin_amdgcn_mfma_f32_16x16x32_bf16(a0, b0, d, 0, 0, 0);
    d = __builtin_amdgcn_mfma_f32_16x16x32_bf16(a1, b1, d, 0, 0, 0);
#pragma unroll
    for (int j = 0; j < 4; ++j) zs[j] += exp2f(d[j]);
  }
#pragma unroll
  for (int j = 0; j < 4; ++j) {
    float v = zs[j];
    v += __shfl_xor(v, 1);
    v += __shfl_xor(v, 2);
    v += __shfl_xor(v, 4);
    v += __shfl_xor(v, 8);
    if (lo == 0) invZ[bh * 1024 + s_base + hi * 4 + j] = 1.0f / v;
  }
}

__global__ __launch_bounds__(256) void attn_pass2(const ushort_t* __restrict__ qhT,
                                                  const ushort_t* __restrict__ khT,
                                                  const ushort_t* __restrict__ vh,
                                                  const float* __restrict__ invZ,
                                                  float* __restrict__ out) {
  __shared__ ushort_t Pt[4][16][32];
  int bh = blockIdx.y;
  int lane = threadIdx.x & 63, wave = threadIdx.x >> 6;
  int lo = lane & 15, hi = lane >> 4;
  int t0 = blockIdx.x * 64 + wave * 16;
  const ushort_t* qb = qhT + ((size_t)bh << 16);
  const ushort_t* kb = khT + ((size_t)bh << 16);
  const ushort_t* vb = vh + ((size_t)bh << 16);
  const float* izb = invZ + bh * 1024;

  short8 bq0 = *reinterpret_cast<const short8*>(qb + (size_t)(t0 + lo) * 64 + hi * 8);
  short8 bq1 = *reinterpret_cast<const short8*>(qb + (size_t)(t0 + lo) * 64 + 32 + hi * 8);

  f32x4 facc[4] = {};

  for (int s0 = 0; s0 < 1024; s0 += 32) {
#pragma unroll
    for (int st = 0; st < 2; ++st) {
      int sb = s0 + st * 16;
      short8 ak0 = *reinterpret_cast<const short8*>(kb + (size_t)(sb + lo) * 64 + hi * 8);
      short8 ak1 = *reinterpret_cast<const short8*>(kb + (size_t)(sb + lo) * 64 + 32 + hi * 8);
      f32x4 d = {0.f, 0.f, 0.f, 0.f};
      d = __builtin_amdgcn_mfma_f32_16x16x32_bf16(ak0, bq0, d, 0, 0, 0);
      d = __builtin_amdgcn_mfma_f32_16x16x32_bf16(ak1, bq1, d, 0, 0, 0);
      short4v pk;
#pragma unroll
      for (int j = 0; j < 4; ++j)
        pk[j] = (short)f2bf(exp2f(d[j]) * izb[sb + hi * 4 + j]);
      *reinterpret_cast<short4v*>(&Pt[wave][lo][st * 16 + hi * 4]) = pk;
    }
    asm volatile("s_waitcnt lgkmcnt(0)" ::: "memory");
    __builtin_amdgcn_sched_barrier(0);
    short8 bp = *reinterpret_cast<const short8*>(&Pt[wave][lo][hi * 8]);
#pragma unroll
    for (int m = 0; m < 4; ++m) {
      short8 av = *reinterpret_cast<const short8*>(vb + (size_t)(m * 16 + lo) * 1024 + s0 + hi * 8);
      facc[m] = __builtin_amdgcn_mfma_f32_16x16x32_bf16(av, bp, facc[m], 0, 0, 0);
    }
  }

  float* ob = out + ((size_t)bh << 16);
#pragma unroll
  for (int m = 0; m < 4; ++m)
#pragma unroll
    for (int j = 0; j < 4; ++j)
      ob[(size_t)(m * 16 + hi * 4 + j) * 1024 + t0 + lo] = facc[m][j];
}

// ---------------------------------------------------------------------------
extern "C" void kernel_launch(void* const* d_in, const int* in_sizes, int n_in,
                              void* d_out, int out_size, void* d_ws, size_t ws_size,
                              hipStream_t stream) {
  const float* q  = (const float*)d_in[0];
  const float* k  = (const float*)d_in[1];
  const float* v  = (const float*)d_in[2];
  const float* Wq = (const float*)d_in[3];
  const float* bq = (const float*)d_in[4];
  const float* Wk = (const float*)d_in[5];
  const float* bk = (const float*)d_in[6];
  const float* Wv = (const float*)d_in[7];
  const float* bv = (const float*)d_in[8];
  float* out = (float*)d_out;
  char* ws = (char*)d_ws;
  const size_t MB = 1u << 20;

  ushort_t* xTq = (ushort_t*)(ws);            // 16MB; reused as khT
  ushort_t* xTk = (ushort_t*)(ws + 16 * MB);  // 16MB; reused as vh
  ushort_t* xTv = (ushort_t*)(ws + 32 * MB);  // 16MB
  ushort_t* Wqb = (ushort_t*)(ws + 48 * MB);  // 2MB
  ushort_t* Wkb = (ushort_t*)(ws + 50 * MB);  // 2MB
  ushort_t* Wvb = (ushort_t*)(ws + 52 * MB);  // 2MB
  ushort_t* qhT = (ushort_t*)(ws + 54 * MB);  // 16MB
  ushort_t* khT = xTq;
  ushort_t* vhb = xTk;
  float*    invZ = (float*)(ws + 70 * MB);    // 0.5MB
  ushort_t* Pbuf = (ushort_t*)(ws + 72 * MB); // 256MB (big-ws path only)
  bool bigws = ws_size >= (328ULL << 20);

  dim3 tb(256);
  transpose_cvt<<<dim3(16, 16, 8), tb, 0, stream>>>(q, xTq);
  transpose_cvt<<<dim3(16, 16, 8), tb, 0, stream>>>(k, xTk);
  transpose_cvt<<<dim3(16, 16, 8), tb, 0, stream>>>(v, xTv);
  cvt_bf16<<<dim3(1024), tb, 0, stream>>>(Wq, Wqb, QSCALE);
  cvt_bf16<<<dim3(1024), tb, 0, stream>>>(Wk, Wkb, 1.0f);
  cvt_bf16<<<dim3(1024), tb, 0, stream>>>(Wv, Wvb, 1.0f);
  gemm_bt<true ><<<dim3(8, 8, 8), tb, 0, stream>>>(Wqb, xTq, bq, QSCALE, qhT);
  gemm_bt<true ><<<dim3(8, 8, 8), tb, 0, stream>>>(Wkb, xTk, bk, 1.0f, khT);
  gemm_bt<false><<<dim3(8, 8, 8), tb, 0, stream>>>(Wvb, xTv, bv, 1.0f, vhb);
  if (bigws) {
    attn_p1<<<dim3(8, 128), tb, 0, stream>>>(qhT, khT, Pbuf, invZ);
    vscale<<<dim3(32, 128), tb, 0, stream>>>(vhb, invZ);
    gemm_pv<<<dim3(8, 128), tb, 0, stream>>>(vhb, Pbuf, out);
  } else {
    attn_pass1<<<dim3(16, 128), tb, 0, stream>>>(qhT, khT, invZ);
    attn_pass2<<<dim3(16, 128), tb, 0, stream>>>(qhT, khT, vhb, invZ, out);
  }
}

// Round 4
// 340.349 us; speedup vs baseline: 1.8658x; 1.8370x over previous
//
#include <hip/hip_runtime.h>
#include <stdint.h>

typedef unsigned short ushort_t;
typedef float  f32x4  __attribute__((ext_vector_type(4)));
typedef short  short8 __attribute__((ext_vector_type(8)));
typedef short  short4v __attribute__((ext_vector_type(4)));

// softmax base-2: scores pre-scaled by (1/8)*log2(e) folded into Q projection.
#define QSCALE 0.18033688011112043f

__device__ __forceinline__ ushort_t f2bf(float f) {
  unsigned u = __builtin_bit_cast(unsigned, f);
  unsigned r = (u + 0x7fffu + ((u >> 16) & 1u)) >> 16;
  return (ushort_t)r;
}
__device__ __forceinline__ float bf2f(ushort_t u) {
  unsigned x = (unsigned)u << 16;
  return __builtin_bit_cast(float, x);
}

typedef const __attribute__((address_space(1))) unsigned int* gas_t;
typedef __attribute__((address_space(3))) unsigned int* las_t;
__device__ __forceinline__ void gload16(const void* g, void* l) {
  __builtin_amdgcn_global_load_lds((gas_t)g, (las_t)l, 16, 0, 0);
}

// ---------------------------------------------------------------------------
// (B,C,L) f32 -> (B,L,C) bf16 transpose+convert. 64x64 tiles, 256 threads.
__global__ __launch_bounds__(256) void transpose_cvt(const float* __restrict__ in,
                                                     ushort_t* __restrict__ out) {
  __shared__ float tile[64][65];
  int b  = blockIdx.z;
  int c0 = blockIdx.x * 64, l0 = blockIdx.y * 64;
  int col = threadIdx.x & 63;
  int row4 = threadIdx.x >> 6;
  const float* p = in + ((size_t)b * 1024 + c0) * 1024 + l0;
#pragma unroll
  for (int i = 0; i < 16; ++i) {
    int r = row4 * 16 + i;
    tile[r][col] = p[(size_t)r * 1024 + col];
  }
  __syncthreads();
  ushort_t* q = out + ((size_t)b * 1024 + l0) * 1024 + c0;
#pragma unroll
  for (int i = 0; i < 16; ++i) {
    int r = row4 * 16 + i;
    q[(size_t)r * 1024 + col] = f2bf(tile[col][r]);
  }
}

// flat f32 -> bf16 with scale; grid*256*4 == n exactly
__global__ __launch_bounds__(256) void cvt_bf16(const float* __restrict__ in,
                                                ushort_t* __restrict__ out, float sc) {
  int i = blockIdx.x * 256 + threadIdx.x;
  f32x4 v = *reinterpret_cast<const f32x4*>(in + (size_t)i * 4);
  short4v pk;
#pragma unroll
  for (int j = 0; j < 4; ++j) pk[j] = (short)f2bf(v[j] * sc);
  *reinterpret_cast<short4v*>(out + (size_t)i * 4) = pk;
}

// ---------------------------------------------------------------------------
// C[o,l] = sum_c A[o,c]*BT[l,c] + bias[o]*bs. 128x128 tile, BK=32,
// global_load_lds width-16 staging, 4 waves each 64x64 (4x4 frags 16x16x32).
template <bool OUT_T>
__global__ __launch_bounds__(256) void gemm_bt(const ushort_t* __restrict__ A,
                                               const ushort_t* __restrict__ BT,
                                               const float* __restrict__ bias,
                                               float bs,
                                               ushort_t* __restrict__ outp) {
  __shared__ ushort_t As[128 * 32];
  __shared__ ushort_t Bs[128 * 32];
  int b = blockIdx.z;
  int Mbase = blockIdx.y * 128, Nbase = blockIdx.x * 128;
  int tid = threadIdx.x;
  int lane = tid & 63, wave = tid >> 6;
  int wr = wave >> 1, wc = wave & 1;
  int lo = lane & 15, hi = lane >> 4;
  const ushort_t* Bb = BT + ((size_t)b << 20);

  f32x4 acc[4][4] = {};

  for (int kt = 0; kt < 1024; kt += 32) {
#pragma unroll
    for (int it = 0; it < 2; ++it) {
      int cch = tid + it * 256;
      int r = cch >> 2, p = cch & 3;
      gload16(A + (size_t)(Mbase + r) * 1024 + kt + p * 8, &As[it * 2048 + wave * 512]);
      gload16(Bb + (size_t)(Nbase + r) * 1024 + kt + p * 8, &Bs[it * 2048 + wave * 512]);
    }
    __syncthreads();
    short8 af[4], bf[4];
#pragma unroll
    for (int m = 0; m < 4; ++m)
      af[m] = *reinterpret_cast<const short8*>(&As[(wr * 64 + m * 16 + lo) * 32 + hi * 8]);
#pragma unroll
    for (int n = 0; n < 4; ++n)
      bf[n] = *reinterpret_cast<const short8*>(&Bs[(wc * 64 + n * 16 + lo) * 32 + hi * 8]);
#pragma unroll
    for (int m = 0; m < 4; ++m)
#pragma unroll
      for (int n = 0; n < 4; ++n)
        acc[m][n] = __builtin_amdgcn_mfma_f32_16x16x32_bf16(af[m], bf[n], acc[m][n], 0, 0, 0);
    __syncthreads();
  }

#pragma unroll
  for (int m = 0; m < 4; ++m) {
    int o0 = Mbase + wr * 64 + m * 16 + hi * 4;
#pragma unroll
    for (int n = 0; n < 4; ++n) {
      int col = Nbase + wc * 64 + n * 16 + lo;
      if (OUT_T) {
        short4v pk;
#pragma unroll
        for (int j = 0; j < 4; ++j) pk[j] = (short)f2bf(acc[m][n][j] + bias[o0 + j] * bs);
        *reinterpret_cast<short4v*>(outp + ((size_t)b << 20) + ((size_t)(o0 >> 6) << 16) +
                                    (size_t)col * 64 + (o0 & 63)) = pk;
      } else {
#pragma unroll
        for (int j = 0; j < 4; ++j)
          outp[((size_t)b << 20) + (size_t)(o0 + j) * 1024 + col] =
              f2bf(acc[m][n][j] + bias[o0 + j] * bs);
      }
    }
  }
}

// ---------------------------------------------------------------------------
// attn_z: invZ[bh][s] = 1 / sum_t 2^(q_t . k_s). Block = (bh, 128 s).
// K-frags register-resident; Q streamed in 128-t steps. 4 waves 2x2 (s x t).
__global__ __launch_bounds__(256) void attn_z(const ushort_t* __restrict__ qhT,
                                              const ushort_t* __restrict__ khT,
                                              float* __restrict__ invZ) {
  __shared__ float zbuf[2][2][64];
  int bid = blockIdx.y * 8 + blockIdx.x;
  int logical = (bid & 7) * 128 + (bid >> 3);   // XCD-bijective swizzle (1024=8*128)
  int sblk = logical & 7, bh = logical >> 3;
  int tid = threadIdx.x;
  int lane = tid & 63, wave = tid >> 6;
  int wr = wave >> 1, wc = wave & 1;
  int lo = lane & 15, hi = lane >> 4;
  const ushort_t* kb = khT + ((size_t)bh << 16);
  const ushort_t* qb = qhT + ((size_t)bh << 16);

  int sbase = sblk * 128 + wr * 64;
  short8 af[4][2];
#pragma unroll
  for (int m = 0; m < 4; ++m)
#pragma unroll
    for (int kk = 0; kk < 2; ++kk)
      af[m][kk] = *reinterpret_cast<const short8*>(
          kb + (size_t)(sbase + m * 16 + lo) * 64 + kk * 32 + hi * 8);

  float zp[4][4] = {};

  for (int t0 = 0; t0 < 1024; t0 += 128) {
    int tbase = t0 + wc * 64;
    short8 bf[4][2];
#pragma unroll
    for (int n = 0; n < 4; ++n)
#pragma unroll
      for (int kk = 0; kk < 2; ++kk)
        bf[n][kk] = *reinterpret_cast<const short8*>(
            qb + (size_t)(tbase + n * 16 + lo) * 64 + kk * 32 + hi * 8);
#pragma unroll
    for (int m = 0; m < 4; ++m)
#pragma unroll
      for (int n = 0; n < 4; ++n) {
        f32x4 dd = {0.f, 0.f, 0.f, 0.f};
        dd = __builtin_amdgcn_mfma_f32_16x16x32_bf16(af[m][0], bf[n][0], dd, 0, 0, 0);
        dd = __builtin_amdgcn_mfma_f32_16x16x32_bf16(af[m][1], bf[n][1], dd, 0, 0, 0);
#pragma unroll
        for (int j = 0; j < 4; ++j) zp[m][j] += __builtin_amdgcn_exp2f(dd[j]);
      }
  }
#pragma unroll
  for (int m = 0; m < 4; ++m)
#pragma unroll
    for (int j = 0; j < 4; ++j) {
      float v = zp[m][j];
      v += __shfl_xor(v, 1);
      v += __shfl_xor(v, 2);
      v += __shfl_xor(v, 4);
      v += __shfl_xor(v, 8);
      if (lo == 0) zbuf[wc][wr][m * 16 + hi * 4 + j] = v;
    }
  __syncthreads();
  if (tid < 128) {
    float z = zbuf[0][tid >> 6][tid & 63] + zbuf[1][tid >> 6][tid & 63];
    invZ[bh * 1024 + sblk * 128 + tid] = 1.0f / z;
  }
}

// ---------------------------------------------------------------------------
// vh[bh][d][s] *= invZ[bh][s], in place. grid (32, 128).
__global__ __launch_bounds__(256) void vscale(ushort_t* __restrict__ vh,
                                              const float* __restrict__ invZ) {
  int bh = blockIdx.y;
  int idx = (blockIdx.x * 256 + threadIdx.x) * 8;
  int s = idx & 1023;
  ushort_t* p = vh + ((size_t)bh << 16) + idx;
  const float* iz = invZ + bh * 1024 + s;
  short8 v = *reinterpret_cast<const short8*>(p);
  short8 o;
#pragma unroll
  for (int j = 0; j < 8; ++j) o[j] = (short)f2bf(bf2f((ushort_t)v[j]) * iz[j]);
  *reinterpret_cast<short8*>(p) = o;
}

// ---------------------------------------------------------------------------
// attn_av: out[bh][d][t] = sum_s 2^(q_t.k_s) * Vs[d][s]   (Vs pre-scaled by invZ)
// Block = (bh, 128 t); 4 waves x 32 t. s-tiles of 64 staged in LDS
// (K [s][d], V [d][s], XOR-swizzled via pre-swizzled global source, rule #21).
// Per s-tile per wave: 16 QK MFMA -> 32 exp2 -> P^T via per-wave swizzled LDS
// -> 16 PV MFMA.
__global__ __launch_bounds__(256) void attn_av(const ushort_t* __restrict__ qhT,
                                               const ushort_t* __restrict__ khT,
                                               const ushort_t* __restrict__ vs,
                                               float* __restrict__ out) {
  __shared__ ushort_t Ks[64 * 64];      // [s][d] rows 128B, swz ((s&7)<<4)
  __shared__ ushort_t Vt[64 * 64];      // [d][s] rows 128B, swz ((d&7)<<4)
  __shared__ ushort_t Pt[4][32 * 64];   // per-wave [t][s] rows 128B, swz ((t&7)<<4)
  int bid = blockIdx.y * 8 + blockIdx.x;
  int logical = (bid & 7) * 128 + (bid >> 3);   // XCD-bijective swizzle
  int tblk = logical & 7, bh = logical >> 3;
  int tid = threadIdx.x;
  int lane = tid & 63, wave = tid >> 6;
  int lo = lane & 15, hi = lane >> 4;
  const ushort_t* qb = qhT + ((size_t)bh << 16);
  const char* kbase = (const char*)(khT + ((size_t)bh << 16));
  const char* vbase = (const char*)(vs + ((size_t)bh << 16));
  int t0 = tblk * 128 + wave * 32;

  // resident Q fragments: 32 t rows per wave
  short8 bq[2][2];
#pragma unroll
  for (int n = 0; n < 2; ++n)
#pragma unroll
    for (int kk = 0; kk < 2; ++kk)
      bq[n][kk] = *reinterpret_cast<const short8*>(
          qb + (size_t)(t0 + n * 16 + lo) * 64 + kk * 32 + hi * 8);

  f32x4 acc[4][2] = {};
  char* pw = (char*)Pt[wave];
  int swl = (lo & 7) << 4;

  for (int s0 = 0; s0 < 1024; s0 += 64) {
    // stage K and V tiles (8KB each): linear LDS dest, inverse-swizzled source
#pragma unroll
    for (int r = 0; r < 2; ++r) {
      int L = r * 4096 + tid * 16;
      int row = L >> 7;
      int off = (L & 127) ^ ((row & 7) << 4);
      gload16(kbase + (size_t)(s0 + row) * 128 + off,
              (char*)Ks + r * 4096 + wave * 1024);
      gload16(vbase + (size_t)row * 2048 + (size_t)s0 * 2 + off,
              (char*)Vt + r * 4096 + wave * 1024);
    }
    __syncthreads();

    // QK^T (S^T[s=64][t=32]) -> exp2 -> P^T to per-wave LDS
#pragma unroll
    for (int m = 0; m < 4; ++m) {
      int srow = m * 16 + lo;
      int sws = (srow & 7) << 4;
      short8 af0 = *reinterpret_cast<const short8*>(
          (char*)Ks + srow * 128 + ((hi * 16) ^ sws));
      short8 af1 = *reinterpret_cast<const short8*>(
          (char*)Ks + srow * 128 + ((64 + hi * 16) ^ sws));
#pragma unroll
      for (int n = 0; n < 2; ++n) {
        f32x4 dd = {0.f, 0.f, 0.f, 0.f};
        dd = __builtin_amdgcn_mfma_f32_16x16x32_bf16(af0, bq[n][0], dd, 0, 0, 0);
        dd = __builtin_amdgcn_mfma_f32_16x16x32_bf16(af1, bq[n][1], dd, 0, 0, 0);
        short4v pk;
#pragma unroll
        for (int j = 0; j < 4; ++j) pk[j] = (short)f2bf(__builtin_amdgcn_exp2f(dd[j]));
        // t = n*16+lo, s bytes = (m*16+hi*4)*2
        *reinterpret_cast<short4v*>(
            pw + (n * 16 + lo) * 128 + ((m * 32 + hi * 8) ^ ((lo & 7) << 4))) = pk;
      }
    }
    asm volatile("s_waitcnt lgkmcnt(0)" ::: "memory");
    __builtin_amdgcn_sched_barrier(0);

    // PV: out[d=64][t=32] += V[d][s] * P[t][s]
    short8 bp[2][2];
#pragma unroll
    for (int n = 0; n < 2; ++n)
#pragma unroll
      for (int kk = 0; kk < 2; ++kk)
        bp[n][kk] = *reinterpret_cast<const short8*>(
            pw + (n * 16 + lo) * 128 + ((kk * 64 + hi * 16) ^ swl));
#pragma unroll
    for (int m = 0; m < 4; ++m) {
      int drow = m * 16 + lo;
      int swd = (drow & 7) << 4;
      short8 av0 = *reinterpret_cast<const short8*>(
          (char*)Vt + drow * 128 + ((hi * 16) ^ swd));
      short8 av1 = *reinterpret_cast<const short8*>(
          (char*)Vt + drow * 128 + ((64 + hi * 16) ^ swd));
#pragma unroll
      for (int n = 0; n < 2; ++n) {
        acc[m][n] = __builtin_amdgcn_mfma_f32_16x16x32_bf16(av0, bp[n][0], acc[m][n], 0, 0, 0);
        acc[m][n] = __builtin_amdgcn_mfma_f32_16x16x32_bf16(av1, bp[n][1], acc[m][n], 0, 0, 0);
      }
    }
    __syncthreads();
  }

  float* ob = out + ((size_t)bh << 16);
#pragma unroll
  for (int m = 0; m < 4; ++m)
#pragma unroll
    for (int n = 0; n < 2; ++n)
#pragma unroll
      for (int j = 0; j < 4; ++j)
        ob[(size_t)(m * 16 + hi * 4 + j) * 1024 + t0 + n * 16 + lo] = acc[m][n][j];
}

// ---------------------------------------------------------------------------
extern "C" void kernel_launch(void* const* d_in, const int* in_sizes, int n_in,
                              void* d_out, int out_size, void* d_ws, size_t ws_size,
                              hipStream_t stream) {
  const float* q  = (const float*)d_in[0];
  const float* k  = (const float*)d_in[1];
  const float* v  = (const float*)d_in[2];
  const float* Wq = (const float*)d_in[3];
  const float* bq = (const float*)d_in[4];
  const float* Wk = (const float*)d_in[5];
  const float* bk = (const float*)d_in[6];
  const float* Wv = (const float*)d_in[7];
  const float* bv = (const float*)d_in[8];
  float* out = (float*)d_out;
  char* ws = (char*)d_ws;
  const size_t MB = 1u << 20;

  // workspace plan (70.5 MB peak, fits the proven ws floor):
  ushort_t* xTq = (ushort_t*)(ws);            // 16MB; reused as khT
  ushort_t* xTk = (ushort_t*)(ws + 16 * MB);  // 16MB; reused as vh
  ushort_t* xTv = (ushort_t*)(ws + 32 * MB);  // 16MB
  ushort_t* Wqb = (ushort_t*)(ws + 48 * MB);  // 2MB
  ushort_t* Wkb = (ushort_t*)(ws + 50 * MB);  // 2MB
  ushort_t* Wvb = (ushort_t*)(ws + 52 * MB);  // 2MB
  ushort_t* qhT = (ushort_t*)(ws + 54 * MB);  // 16MB
  ushort_t* khT = xTq;
  ushort_t* vhb = xTk;
  float*    invZ = (float*)(ws + 70 * MB);    // 0.5MB

  dim3 tb(256);
  transpose_cvt<<<dim3(16, 16, 8), tb, 0, stream>>>(q, xTq);
  transpose_cvt<<<dim3(16, 16, 8), tb, 0, stream>>>(k, xTk);
  transpose_cvt<<<dim3(16, 16, 8), tb, 0, stream>>>(v, xTv);
  cvt_bf16<<<dim3(1024), tb, 0, stream>>>(Wq, Wqb, QSCALE);
  cvt_bf16<<<dim3(1024), tb, 0, stream>>>(Wk, Wkb, 1.0f);
  cvt_bf16<<<dim3(1024), tb, 0, stream>>>(Wv, Wvb, 1.0f);
  gemm_bt<true ><<<dim3(8, 8, 8), tb, 0, stream>>>(Wqb, xTq, bq, QSCALE, qhT);
  gemm_bt<true ><<<dim3(8, 8, 8), tb, 0, stream>>>(Wkb, xTk, bk, 1.0f, khT);
  gemm_bt<false><<<dim3(8, 8, 8), tb, 0, stream>>>(Wvb, xTv, bv, 1.0f, vhb);
  attn_z<<<dim3(8, 128), tb, 0, stream>>>(qhT, khT, invZ);
  vscale<<<dim3(32, 128), tb, 0, stream>>>(vhb, invZ);
  attn_av<<<dim3(8, 128), tb, 0, stream>>>(qhT, khT, vhb, out);
}

// Round 5
// 333.649 us; speedup vs baseline: 1.9032x; 1.0201x over previous
//
#include <hip/hip_runtime.h>
#include <stdint.h>

typedef unsigned short ushort_t;
typedef float  f32x4  __attribute__((ext_vector_type(4)));
typedef short  short8 __attribute__((ext_vector_type(8)));
typedef short  short4v __attribute__((ext_vector_type(4)));

// softmax base-2: scores pre-scaled by (1/8)*log2(e) folded into Q projection.
#define QSCALE 0.18033688011112043f

__device__ __forceinline__ ushort_t f2bf(float f) {
  unsigned u = __builtin_bit_cast(unsigned, f);
  unsigned r = (u + 0x7fffu + ((u >> 16) & 1u)) >> 16;
  return (ushort_t)r;
}
__device__ __forceinline__ float bf2f(ushort_t u) {
  unsigned x = (unsigned)u << 16;
  return __builtin_bit_cast(float, x);
}

typedef const __attribute__((address_space(1))) unsigned int* gas_t;
typedef __attribute__((address_space(3))) unsigned int* las_t;
__device__ __forceinline__ void gload16(const void* g, void* l) {
  __builtin_amdgcn_global_load_lds((gas_t)g, (las_t)l, 16, 0, 0);
}

// ---------------------------------------------------------------------------
// merged: q,k,v (B,C,L) f32 -> (B,L,C) bf16 transpose+convert. grid (16,16,24).
__global__ __launch_bounds__(256) void transpose_cvt3(
    const float* __restrict__ q, const float* __restrict__ k,
    const float* __restrict__ v, ushort_t* __restrict__ oq,
    ushort_t* __restrict__ ok, ushort_t* __restrict__ ov) {
  __shared__ float tile[64][65];
  int z = blockIdx.z;
  int t = z >> 3, b = z & 7;
  const float* in = (t == 0) ? q : (t == 1) ? k : v;
  ushort_t* out = (t == 0) ? oq : (t == 1) ? ok : ov;
  int c0 = blockIdx.x * 64, l0 = blockIdx.y * 64;
  int col = threadIdx.x & 63;
  int row4 = threadIdx.x >> 6;
  const float* p = in + ((size_t)b * 1024 + c0) * 1024 + l0;
#pragma unroll
  for (int i = 0; i < 16; ++i) {
    int r = row4 * 16 + i;
    tile[r][col] = p[(size_t)r * 1024 + col];
  }
  __syncthreads();
  ushort_t* qo = out + ((size_t)b * 1024 + l0) * 1024 + c0;
#pragma unroll
  for (int i = 0; i < 16; ++i) {
    int r = row4 * 16 + i;
    qo[(size_t)r * 1024 + col] = f2bf(tile[col][r]);
  }
}

// merged weight cvt: 3 x 2^20 f32 -> bf16 (seg 0 scaled by QSCALE). grid 3072.
__global__ __launch_bounds__(256) void cvt_w3(
    const float* __restrict__ Wq, const float* __restrict__ Wk,
    const float* __restrict__ Wv, ushort_t* __restrict__ oq,
    ushort_t* __restrict__ ok, ushort_t* __restrict__ ov) {
  int seg = blockIdx.x >> 10;
  const float* in = (seg == 0) ? Wq : (seg == 1) ? Wk : Wv;
  ushort_t* out = (seg == 0) ? oq : (seg == 1) ? ok : ov;
  float sc = (seg == 0) ? QSCALE : 1.0f;
  int i = (blockIdx.x & 1023) * 256 + threadIdx.x;
  f32x4 v = *reinterpret_cast<const f32x4*>(in + (size_t)i * 4);
  short4v pk;
#pragma unroll
  for (int j = 0; j < 4; ++j) pk[j] = (short)f2bf(v[j] * sc);
  *reinterpret_cast<short4v*>(out + (size_t)i * 4) = pk;
}

// ---------------------------------------------------------------------------
// C[o,l] = sum_c A[o,c]*BT[l,c] + bias[o]*bs. 128x128 tile, BK=32,
// global_load_lds width-16 staging, 4 waves each 64x64 (4x4 frags 16x16x32).
template <bool OUT_T>
__global__ __launch_bounds__(256) void gemm_bt(const ushort_t* __restrict__ A,
                                               const ushort_t* __restrict__ BT,
                                               const float* __restrict__ bias,
                                               float bs,
                                               ushort_t* __restrict__ outp) {
  __shared__ ushort_t As[128 * 32];
  __shared__ ushort_t Bs[128 * 32];
  int b = blockIdx.z;
  int Mbase = blockIdx.y * 128, Nbase = blockIdx.x * 128;
  int tid = threadIdx.x;
  int lane = tid & 63, wave = tid >> 6;
  int wr = wave >> 1, wc = wave & 1;
  int lo = lane & 15, hi = lane >> 4;
  const ushort_t* Bb = BT + ((size_t)b << 20);

  f32x4 acc[4][4] = {};

  for (int kt = 0; kt < 1024; kt += 32) {
#pragma unroll
    for (int it = 0; it < 2; ++it) {
      int cch = tid + it * 256;
      int r = cch >> 2, p = cch & 3;
      gload16(A + (size_t)(Mbase + r) * 1024 + kt + p * 8, &As[it * 2048 + wave * 512]);
      gload16(Bb + (size_t)(Nbase + r) * 1024 + kt + p * 8, &Bs[it * 2048 + wave * 512]);
    }
    __syncthreads();
    short8 af[4], bf[4];
#pragma unroll
    for (int m = 0; m < 4; ++m)
      af[m] = *reinterpret_cast<const short8*>(&As[(wr * 64 + m * 16 + lo) * 32 + hi * 8]);
#pragma unroll
    for (int n = 0; n < 4; ++n)
      bf[n] = *reinterpret_cast<const short8*>(&Bs[(wc * 64 + n * 16 + lo) * 32 + hi * 8]);
#pragma unroll
    for (int m = 0; m < 4; ++m)
#pragma unroll
      for (int n = 0; n < 4; ++n)
        acc[m][n] = __builtin_amdgcn_mfma_f32_16x16x32_bf16(af[m], bf[n], acc[m][n], 0, 0, 0);
    __syncthreads();
  }

#pragma unroll
  for (int m = 0; m < 4; ++m) {
    int o0 = Mbase + wr * 64 + m * 16 + hi * 4;
#pragma unroll
    for (int n = 0; n < 4; ++n) {
      int col = Nbase + wc * 64 + n * 16 + lo;
      if (OUT_T) {
        short4v pk;
#pragma unroll
        for (int j = 0; j < 4; ++j) pk[j] = (short)f2bf(acc[m][n][j] + bias[o0 + j] * bs);
        *reinterpret_cast<short4v*>(outp + ((size_t)b << 20) + ((size_t)(o0 >> 6) << 16) +
                                    (size_t)col * 64 + (o0 & 63)) = pk;
      } else {
#pragma unroll
        for (int j = 0; j < 4; ++j)
          outp[((size_t)b << 20) + (size_t)(o0 + j) * 1024 + col] =
              f2bf(acc[m][n][j] + bias[o0 + j] * bs);
      }
    }
  }
}

// ---------------------------------------------------------------------------
// attn_zs: z[s] = sum_t 2^(q_t . k_s) for this block's 128 s; then scales
// V[bh][:, s-slice] by 1/z in place (fused vscale; invZ never leaves LDS).
__global__ __launch_bounds__(256) void attn_zs(const ushort_t* __restrict__ qhT,
                                               const ushort_t* __restrict__ khT,
                                               ushort_t* __restrict__ vhb) {
  __shared__ float zbuf[2][2][64];
  __shared__ float invs[128];
  int bid = blockIdx.y * 8 + blockIdx.x;
  int logical = (bid & 7) * 128 + (bid >> 3);   // XCD-bijective swizzle (1024=8*128)
  int sblk = logical & 7, bh = logical >> 3;
  int tid = threadIdx.x;
  int lane = tid & 63, wave = tid >> 6;
  int wr = wave >> 1, wc = wave & 1;
  int lo = lane & 15, hi = lane >> 4;
  const ushort_t* kb = khT + ((size_t)bh << 16);
  const ushort_t* qb = qhT + ((size_t)bh << 16);

  int sbase = sblk * 128 + wr * 64;
  short8 af[4][2];
#pragma unroll
  for (int m = 0; m < 4; ++m)
#pragma unroll
    for (int kk = 0; kk < 2; ++kk)
      af[m][kk] = *reinterpret_cast<const short8*>(
          kb + (size_t)(sbase + m * 16 + lo) * 64 + kk * 32 + hi * 8);

  float zp[4][4] = {};

  for (int t0 = 0; t0 < 1024; t0 += 128) {
    int tbase = t0 + wc * 64;
    short8 bf[4][2];
#pragma unroll
    for (int n = 0; n < 4; ++n)
#pragma unroll
      for (int kk = 0; kk < 2; ++kk)
        bf[n][kk] = *reinterpret_cast<const short8*>(
            qb + (size_t)(tbase + n * 16 + lo) * 64 + kk * 32 + hi * 8);
#pragma unroll
    for (int m = 0; m < 4; ++m)
#pragma unroll
      for (int n = 0; n < 4; ++n) {
        f32x4 dd = {0.f, 0.f, 0.f, 0.f};
        __builtin_amdgcn_s_setprio(1);
        dd = __builtin_amdgcn_mfma_f32_16x16x32_bf16(af[m][0], bf[n][0], dd, 0, 0, 0);
        dd = __builtin_amdgcn_mfma_f32_16x16x32_bf16(af[m][1], bf[n][1], dd, 0, 0, 0);
        __builtin_amdgcn_s_setprio(0);
#pragma unroll
        for (int j = 0; j < 4; ++j) zp[m][j] += __builtin_amdgcn_exp2f(dd[j]);
      }
  }
#pragma unroll
  for (int m = 0; m < 4; ++m)
#pragma unroll
    for (int j = 0; j < 4; ++j) {
      float v = zp[m][j];
      v += __shfl_xor(v, 1);
      v += __shfl_xor(v, 2);
      v += __shfl_xor(v, 4);
      v += __shfl_xor(v, 8);
      if (lo == 0) zbuf[wc][wr][m * 16 + hi * 4 + j] = v;
    }
  __syncthreads();
  if (tid < 128)
    invs[tid] = 1.0f / (zbuf[0][tid >> 6][tid & 63] + zbuf[1][tid >> 6][tid & 63]);
  __syncthreads();

  // scale V[bh][d=0..63][sblk*128 .. +128) in place
  int d = tid >> 2, soff = (tid & 3) * 32;
  ushort_t* vp = vhb + ((size_t)bh << 16) + (size_t)d * 1024 + sblk * 128 + soff;
#pragma unroll
  for (int c = 0; c < 4; ++c) {
    short8 vv = *reinterpret_cast<const short8*>(vp + c * 8);
    short8 o;
#pragma unroll
    for (int j = 0; j < 8; ++j)
      o[j] = (short)f2bf(bf2f((ushort_t)vv[j]) * invs[soff + c * 8 + j]);
    *reinterpret_cast<short8*>(vp + c * 8) = o;
  }
}

// ---------------------------------------------------------------------------
// attn_av: out[bh][d][t] = sum_s 2^(q_t.k_s) * Vs[d][s]   (Vs pre-scaled).
// Double-buffered K/V staging (raw s_barrier + counted vmcnt(4), T3-min),
// setprio around MFMA clusters, XOR-swizzled LDS (rule #21).
__global__ __launch_bounds__(256) void attn_av(const ushort_t* __restrict__ qhT,
                                               const ushort_t* __restrict__ khT,
                                               const ushort_t* __restrict__ vs,
                                               float* __restrict__ out) {
  __shared__ ushort_t Ks[2][64 * 64];   // [s][d] rows 128B, swz ((s&7)<<4)
  __shared__ ushort_t Vt[2][64 * 64];   // [d][s] rows 128B, swz ((d&7)<<4)
  __shared__ ushort_t Pt[4][32 * 64];   // per-wave [t][s] rows 128B, swz ((t&7)<<4)
  int bid = blockIdx.y * 8 + blockIdx.x;
  int logical = (bid & 7) * 128 + (bid >> 3);   // XCD-bijective swizzle
  int tblk = logical & 7, bh = logical >> 3;
  int tid = threadIdx.x;
  int lane = tid & 63, wave = tid >> 6;
  int lo = lane & 15, hi = lane >> 4;
  const ushort_t* qb = qhT + ((size_t)bh << 16);
  const char* kbase = (const char*)(khT + ((size_t)bh << 16));
  const char* vbase = (const char*)(vs + ((size_t)bh << 16));
  int t0 = tblk * 128 + wave * 32;

  // resident Q fragments: 32 t rows per wave
  short8 bq[2][2];
#pragma unroll
  for (int n = 0; n < 2; ++n)
#pragma unroll
    for (int kk = 0; kk < 2; ++kk)
      bq[n][kk] = *reinterpret_cast<const short8*>(
          qb + (size_t)(t0 + n * 16 + lo) * 64 + kk * 32 + hi * 8);

  f32x4 acc[4][2] = {};
  char* pw = (char*)Pt[wave];
  int swl = (lo & 7) << 4;

  auto stageKV = [&](int buf, int s0) {
#pragma unroll
    for (int r = 0; r < 2; ++r) {
      int L = r * 4096 + tid * 16;
      int row = L >> 7;
      int off = (L & 127) ^ ((row & 7) << 4);
      gload16(kbase + (size_t)(s0 + row) * 128 + off,
              (char*)Ks + buf * 8192 + r * 4096 + wave * 1024);
      gload16(vbase + (size_t)row * 2048 + (size_t)s0 * 2 + off,
              (char*)Vt + buf * 8192 + r * 4096 + wave * 1024);
    }
  };

  auto computeTile = [&](int buf) {
    char* ksb = (char*)Ks + buf * 8192;
    char* vtb = (char*)Vt + buf * 8192;
    // QK^T (S^T[s=64][t=32]) -> exp2 -> P^T to per-wave LDS
#pragma unroll
    for (int m = 0; m < 4; ++m) {
      int srow = m * 16 + lo;
      int sws = (srow & 7) << 4;
      short8 af0 = *reinterpret_cast<const short8*>(ksb + srow * 128 + ((hi * 16) ^ sws));
      short8 af1 = *reinterpret_cast<const short8*>(ksb + srow * 128 + ((64 + hi * 16) ^ sws));
#pragma unroll
      for (int n = 0; n < 2; ++n) {
        f32x4 dd = {0.f, 0.f, 0.f, 0.f};
        __builtin_amdgcn_s_setprio(1);
        dd = __builtin_amdgcn_mfma_f32_16x16x32_bf16(af0, bq[n][0], dd, 0, 0, 0);
        dd = __builtin_amdgcn_mfma_f32_16x16x32_bf16(af1, bq[n][1], dd, 0, 0, 0);
        __builtin_amdgcn_s_setprio(0);
        short4v pk;
#pragma unroll
        for (int j = 0; j < 4; ++j) pk[j] = (short)f2bf(__builtin_amdgcn_exp2f(dd[j]));
        *reinterpret_cast<short4v*>(
            pw + (n * 16 + lo) * 128 + ((m * 32 + hi * 8) ^ swl)) = pk;
      }
    }
    asm volatile("s_waitcnt lgkmcnt(0)" ::: "memory");
    __builtin_amdgcn_sched_barrier(0);

    // PV: out[d=64][t=32] += V[d][s] * P[t][s]
    short8 bp[2][2];
#pragma unroll
    for (int n = 0; n < 2; ++n)
#pragma unroll
      for (int kk = 0; kk < 2; ++kk)
        bp[n][kk] = *reinterpret_cast<const short8*>(
            pw + (n * 16 + lo) * 128 + ((kk * 64 + hi * 16) ^ swl));
    __builtin_amdgcn_s_setprio(1);
#pragma unroll
    for (int m = 0; m < 4; ++m) {
      int drow = m * 16 + lo;
      int swd = (drow & 7) << 4;
      short8 av0 = *reinterpret_cast<const short8*>(vtb + drow * 128 + ((hi * 16) ^ swd));
      short8 av1 = *reinterpret_cast<const short8*>(vtb + drow * 128 + ((64 + hi * 16) ^ swd));
#pragma unroll
      for (int n = 0; n < 2; ++n) {
        acc[m][n] = __builtin_amdgcn_mfma_f32_16x16x32_bf16(av0, bp[n][0], acc[m][n], 0, 0, 0);
        acc[m][n] = __builtin_amdgcn_mfma_f32_16x16x32_bf16(av1, bp[n][1], acc[m][n], 0, 0, 0);
      }
    }
    __builtin_amdgcn_s_setprio(0);
  };

  stageKV(0, 0);
#pragma unroll 1
  for (int i = 0; i < 15; ++i) {
    stageKV((i + 1) & 1, (i + 1) * 64);
    asm volatile("s_waitcnt vmcnt(4)" ::: "memory");
    __builtin_amdgcn_s_barrier();
    __builtin_amdgcn_sched_barrier(0);
    computeTile(i & 1);
    __builtin_amdgcn_s_barrier();
  }
  asm volatile("s_waitcnt vmcnt(0)" ::: "memory");
  __builtin_amdgcn_s_barrier();
  __builtin_amdgcn_sched_barrier(0);
  computeTile(1);

  float* ob = out + ((size_t)bh << 16);
#pragma unroll
  for (int m = 0; m < 4; ++m)
#pragma unroll
    for (int n = 0; n < 2; ++n)
#pragma unroll
      for (int j = 0; j < 4; ++j)
        ob[(size_t)(m * 16 + hi * 4 + j) * 1024 + t0 + n * 16 + lo] = acc[m][n][j];
}

// ---------------------------------------------------------------------------
extern "C" void kernel_launch(void* const* d_in, const int* in_sizes, int n_in,
                              void* d_out, int out_size, void* d_ws, size_t ws_size,
                              hipStream_t stream) {
  const float* q  = (const float*)d_in[0];
  const float* k  = (const float*)d_in[1];
  const float* v  = (const float*)d_in[2];
  const float* Wq = (const float*)d_in[3];
  const float* bq = (const float*)d_in[4];
  const float* Wk = (const float*)d_in[5];
  const float* bk = (const float*)d_in[6];
  const float* Wv = (const float*)d_in[7];
  const float* bv = (const float*)d_in[8];
  float* out = (float*)d_out;
  char* ws = (char*)d_ws;
  const size_t MB = 1u << 20;

  // workspace plan (70.5 MB peak, fits the proven ws floor):
  ushort_t* xTq = (ushort_t*)(ws);            // 16MB; reused as khT
  ushort_t* xTk = (ushort_t*)(ws + 16 * MB);  // 16MB; reused as vh
  ushort_t* xTv = (ushort_t*)(ws + 32 * MB);  // 16MB
  ushort_t* Wqb = (ushort_t*)(ws + 48 * MB);  // 2MB
  ushort_t* Wkb = (ushort_t*)(ws + 50 * MB);  // 2MB
  ushort_t* Wvb = (ushort_t*)(ws + 52 * MB);  // 2MB
  ushort_t* qhT = (ushort_t*)(ws + 54 * MB);  // 16MB
  ushort_t* khT = xTq;   // written by k-projection AFTER q-projection consumed xTq
  ushort_t* vhb = xTk;   // written by v-projection AFTER k-projection consumed xTk

  dim3 tb(256);
  transpose_cvt3<<<dim3(16, 16, 24), tb, 0, stream>>>(q, k, v, xTq, xTk, xTv);
  cvt_w3<<<dim3(3072), tb, 0, stream>>>(Wq, Wk, Wv, Wqb, Wkb, Wvb);
  gemm_bt<true ><<<dim3(8, 8, 8), tb, 0, stream>>>(Wqb, xTq, bq, QSCALE, qhT);
  gemm_bt<true ><<<dim3(8, 8, 8), tb, 0, stream>>>(Wkb, xTk, bk, 1.0f, khT);
  gemm_bt<false><<<dim3(8, 8, 8), tb, 0, stream>>>(Wvb, xTv, bv, 1.0f, vhb);
  attn_zs<<<dim3(8, 128), tb, 0, stream>>>(qhT, khT, vhb);
  attn_av<<<dim3(8, 128), tb, 0, stream>>>(qhT, khT, vhb, out);
}

// Round 7
// 328.996 us; speedup vs baseline: 1.9302x; 1.0141x over previous
//
#include <hip/hip_runtime.h>
#include <stdint.h>

typedef unsigned short ushort_t;
typedef float  f32x4  __attribute__((ext_vector_type(4)));
typedef short  short8 __attribute__((ext_vector_type(8)));
typedef short  short4v __attribute__((ext_vector_type(4)));

// softmax base-2: scores pre-scaled by (1/8)*log2(e) folded into Q projection.
#define QSCALE 0.18033688011112043f

__device__ __forceinline__ ushort_t f2bf(float f) {
  unsigned u = __builtin_bit_cast(unsigned, f);
  unsigned r = (u + 0x7fffu + ((u >> 16) & 1u)) >> 16;
  return (ushort_t)r;
}
__device__ __forceinline__ float bf2f(ushort_t u) {
  unsigned x = (unsigned)u << 16;
  return __builtin_bit_cast(float, x);
}

typedef const __attribute__((address_space(1))) unsigned int* gas_t;
typedef __attribute__((address_space(3))) unsigned int* las_t;
__device__ __forceinline__ void gload16(const void* g, void* l) {
  __builtin_amdgcn_global_load_lds((gas_t)g, (las_t)l, 16, 0, 0);
}

// ---------------------------------------------------------------------------
// merged: q,k,v (B,C,L) f32 -> (B,L,C) bf16 transpose+convert. grid (16,16,24).
__global__ __launch_bounds__(256) void transpose_cvt3(
    const float* __restrict__ q, const float* __restrict__ k,
    const float* __restrict__ v, ushort_t* __restrict__ oq,
    ushort_t* __restrict__ ok, ushort_t* __restrict__ ov) {
  __shared__ float tile[64][65];
  int z = blockIdx.z;
  int t = z >> 3, b = z & 7;
  const float* in = (t == 0) ? q : (t == 1) ? k : v;
  ushort_t* out = (t == 0) ? oq : (t == 1) ? ok : ov;
  int c0 = blockIdx.x * 64, l0 = blockIdx.y * 64;
  int col = threadIdx.x & 63;
  int row4 = threadIdx.x >> 6;
  const float* p = in + ((size_t)b * 1024 + c0) * 1024 + l0;
#pragma unroll
  for (int i = 0; i < 16; ++i) {
    int r = row4 * 16 + i;
    tile[r][col] = p[(size_t)r * 1024 + col];
  }
  __syncthreads();
  ushort_t* qo = out + ((size_t)b * 1024 + l0) * 1024 + c0;
#pragma unroll
  for (int i = 0; i < 16; ++i) {
    int r = row4 * 16 + i;
    qo[(size_t)r * 1024 + col] = f2bf(tile[col][r]);
  }
}

// merged weight cvt: 3 x 2^20 f32 -> bf16 (seg 0 scaled by QSCALE). grid 3072.
__global__ __launch_bounds__(256) void cvt_w3(
    const float* __restrict__ Wq, const float* __restrict__ Wk,
    const float* __restrict__ Wv, ushort_t* __restrict__ oq,
    ushort_t* __restrict__ ok, ushort_t* __restrict__ ov) {
  int seg = blockIdx.x >> 10;
  const float* in = (seg == 0) ? Wq : (seg == 1) ? Wk : Wv;
  ushort_t* out = (seg == 0) ? oq : (seg == 1) ? ok : ov;
  float sc = (seg == 0) ? QSCALE : 1.0f;
  int i = (blockIdx.x & 1023) * 256 + threadIdx.x;
  f32x4 v = *reinterpret_cast<const f32x4*>(in + (size_t)i * 4);
  short4v pk;
#pragma unroll
  for (int j = 0; j < 4; ++j) pk[j] = (short)f2bf(v[j] * sc);
  *reinterpret_cast<short4v*>(out + (size_t)i * 4) = pk;
}

// ---------------------------------------------------------------------------
// C[o,l] = sum_c A[o,c]*BT[l,c] + bias[o]*bs. 128x128 tile, BK=32,
// global_load_lds width-16 staging, 4 waves each 64x64 (4x4 frags 16x16x32).
// Flat grid 512, batch = bid&7 -> all 64 blocks of a batch on ONE XCD
// (round-robin dispatch): A/B panels fetched ~once per XCD, not ~8x.
template <bool OUT_T>
__global__ __launch_bounds__(256) void gemm_bt(const ushort_t* __restrict__ A,
                                               const ushort_t* __restrict__ BT,
                                               const float* __restrict__ bias,
                                               float bs,
                                               ushort_t* __restrict__ outp) {
  __shared__ ushort_t As[128 * 32];
  __shared__ ushort_t Bs[128 * 32];
  int bid = blockIdx.x;
  int b = bid & 7;
  int within = bid >> 3;
  int Mbase = (within >> 3) * 128, Nbase = (within & 7) * 128;
  int tid = threadIdx.x;
  int lane = tid & 63, wave = tid >> 6;
  int wr = wave >> 1, wc = wave & 1;
  int lo = lane & 15, hi = lane >> 4;
  const ushort_t* Bb = BT + ((size_t)b << 20);

  f32x4 acc[4][4] = {};

  for (int kt = 0; kt < 1024; kt += 32) {
#pragma unroll
    for (int it = 0; it < 2; ++it) {
      int cch = tid + it * 256;
      int r = cch >> 2, p = cch & 3;
      gload16(A + (size_t)(Mbase + r) * 1024 + kt + p * 8, &As[it * 2048 + wave * 512]);
      gload16(Bb + (size_t)(Nbase + r) * 1024 + kt + p * 8, &Bs[it * 2048 + wave * 512]);
    }
    __syncthreads();
    short8 af[4], bf[4];
#pragma unroll
    for (int m = 0; m < 4; ++m)
      af[m] = *reinterpret_cast<const short8*>(&As[(wr * 64 + m * 16 + lo) * 32 + hi * 8]);
#pragma unroll
    for (int n = 0; n < 4; ++n)
      bf[n] = *reinterpret_cast<const short8*>(&Bs[(wc * 64 + n * 16 + lo) * 32 + hi * 8]);
#pragma unroll
    for (int m = 0; m < 4; ++m)
#pragma unroll
      for (int n = 0; n < 4; ++n)
        acc[m][n] = __builtin_amdgcn_mfma_f32_16x16x32_bf16(af[m], bf[n], acc[m][n], 0, 0, 0);
    __syncthreads();
  }

#pragma unroll
  for (int m = 0; m < 4; ++m) {
    int o0 = Mbase + wr * 64 + m * 16 + hi * 4;
#pragma unroll
    for (int n = 0; n < 4; ++n) {
      int col = Nbase + wc * 64 + n * 16 + lo;
      if (OUT_T) {
        short4v pk;
#pragma unroll
        for (int j = 0; j < 4; ++j) pk[j] = (short)f2bf(acc[m][n][j] + bias[o0 + j] * bs);
        *reinterpret_cast<short4v*>(outp + ((size_t)b << 20) + ((size_t)(o0 >> 6) << 16) +
                                    (size_t)col * 64 + (o0 & 63)) = pk;
      } else {
#pragma unroll
        for (int j = 0; j < 4; ++j)
          outp[((size_t)b << 20) + (size_t)(o0 + j) * 1024 + col] =
              f2bf(acc[m][n][j] + bias[o0 + j] * bs);
      }
    }
  }
}

// ---------------------------------------------------------------------------
// attn_zs: z[s] = sum_t 2^(q_t . k_s) for this block's 128 s; then scales
// V[bh][:, s-slice] by 1/z in place (fused vscale; invZ never leaves LDS).
__global__ __launch_bounds__(256) void attn_zs(const ushort_t* __restrict__ qhT,
                                               const ushort_t* __restrict__ khT,
                                               ushort_t* __restrict__ vhb) {
  __shared__ float zbuf[2][2][64];
  __shared__ float invs[128];
  int bid = blockIdx.y * 8 + blockIdx.x;
  int logical = (bid & 7) * 128 + (bid >> 3);   // XCD-bijective swizzle (1024=8*128)
  int sblk = logical & 7, bh = logical >> 3;
  int tid = threadIdx.x;
  int lane = tid & 63, wave = tid >> 6;
  int wr = wave >> 1, wc = wave & 1;
  int lo = lane & 15, hi = lane >> 4;
  const ushort_t* kb = khT + ((size_t)bh << 16);
  const ushort_t* qb = qhT + ((size_t)bh << 16);

  int sbase = sblk * 128 + wr * 64;
  short8 af[4][2];
#pragma unroll
  for (int m = 0; m < 4; ++m)
#pragma unroll
    for (int kk = 0; kk < 2; ++kk)
      af[m][kk] = *reinterpret_cast<const short8*>(
          kb + (size_t)(sbase + m * 16 + lo) * 64 + kk * 32 + hi * 8);

  float zp[4][4] = {};

  for (int t0 = 0; t0 < 1024; t0 += 128) {
    int tbase = t0 + wc * 64;
    short8 bf[4][2];
#pragma unroll
    for (int n = 0; n < 4; ++n)
#pragma unroll
      for (int kk = 0; kk < 2; ++kk)
        bf[n][kk] = *reinterpret_cast<const short8*>(
            qb + (size_t)(tbase + n * 16 + lo) * 64 + kk * 32 + hi * 8);
#pragma unroll
    for (int m = 0; m < 4; ++m)
#pragma unroll
      for (int n = 0; n < 4; ++n) {
        f32x4 dd = {0.f, 0.f, 0.f, 0.f};
        dd = __builtin_amdgcn_mfma_f32_16x16x32_bf16(af[m][0], bf[n][0], dd, 0, 0, 0);
        dd = __builtin_amdgcn_mfma_f32_16x16x32_bf16(af[m][1], bf[n][1], dd, 0, 0, 0);
#pragma unroll
        for (int j = 0; j < 4; ++j) zp[m][j] += __builtin_amdgcn_exp2f(dd[j]);
      }
  }
#pragma unroll
  for (int m = 0; m < 4; ++m)
#pragma unroll
    for (int j = 0; j < 4; ++j) {
      float v = zp[m][j];
      v += __shfl_xor(v, 1);
      v += __shfl_xor(v, 2);
      v += __shfl_xor(v, 4);
      v += __shfl_xor(v, 8);
      if (lo == 0) zbuf[wc][wr][m * 16 + hi * 4 + j] = v;
    }
  __syncthreads();
  if (tid < 128)
    invs[tid] = 1.0f / (zbuf[0][tid >> 6][tid & 63] + zbuf[1][tid >> 6][tid & 63]);
  __syncthreads();

  // scale V[bh][d=0..63][sblk*128 .. +128) in place
  int d = tid >> 2, soff = (tid & 3) * 32;
  ushort_t* vp = vhb + ((size_t)bh << 16) + (size_t)d * 1024 + sblk * 128 + soff;
#pragma unroll
  for (int c = 0; c < 4; ++c) {
    short8 vv = *reinterpret_cast<const short8*>(vp + c * 8);
    short8 o;
#pragma unroll
    for (int j = 0; j < 8; ++j)
      o[j] = (short)f2bf(bf2f((ushort_t)vv[j]) * invs[soff + c * 8 + j]);
    *reinterpret_cast<short8*>(vp + c * 8) = o;
  }
}

// ---------------------------------------------------------------------------
// attn_av: out[bh][d][t] = sum_s 2^(q_t.k_s) * Vs[d][s]   (Vs pre-scaled).
// Single-buffer staging (R4-measured 55.8us structure), XOR-swizzled LDS.
__global__ __launch_bounds__(256) void attn_av(const ushort_t* __restrict__ qhT,
                                               const ushort_t* __restrict__ khT,
                                               const ushort_t* __restrict__ vs,
                                               float* __restrict__ out) {
  __shared__ ushort_t Ks[64 * 64];      // [s][d] rows 128B, swz ((s&7)<<4)
  __shared__ ushort_t Vt[64 * 64];      // [d][s] rows 128B, swz ((d&7)<<4)
  __shared__ ushort_t Pt[4][32 * 64];   // per-wave [t][s] rows 128B, swz ((t&7)<<4)
  int bid = blockIdx.y * 8 + blockIdx.x;
  int logical = (bid & 7) * 128 + (bid >> 3);   // XCD-bijective swizzle
  int tblk = logical & 7, bh = logical >> 3;
  int tid = threadIdx.x;
  int lane = tid & 63, wave = tid >> 6;
  int lo = lane & 15, hi = lane >> 4;
  const ushort_t* qb = qhT + ((size_t)bh << 16);
  const char* kbase = (const char*)(khT + ((size_t)bh << 16));
  const char* vbase = (const char*)(vs + ((size_t)bh << 16));
  int t0 = tblk * 128 + wave * 32;

  // resident Q fragments: 32 t rows per wave
  short8 bq[2][2];
#pragma unroll
  for (int n = 0; n < 2; ++n)
#pragma unroll
    for (int kk = 0; kk < 2; ++kk)
      bq[n][kk] = *reinterpret_cast<const short8*>(
          qb + (size_t)(t0 + n * 16 + lo) * 64 + kk * 32 + hi * 8);

  f32x4 acc[4][2] = {};
  char* pw = (char*)Pt[wave];
  int swl = (lo & 7) << 4;

  for (int s0 = 0; s0 < 1024; s0 += 64) {
    // stage K and V tiles (8KB each): linear LDS dest, inverse-swizzled source
#pragma unroll
    for (int r = 0; r < 2; ++r) {
      int L = r * 4096 + tid * 16;
      int row = L >> 7;
      int off = (L & 127) ^ ((row & 7) << 4);
      gload16(kbase + (size_t)(s0 + row) * 128 + off,
              (char*)Ks + r * 4096 + wave * 1024);
      gload16(vbase + (size_t)row * 2048 + (size_t)s0 * 2 + off,
              (char*)Vt + r * 4096 + wave * 1024);
    }
    __syncthreads();

    // QK^T (S^T[s=64][t=32]) -> exp2 -> P^T to per-wave LDS
#pragma unroll
    for (int m = 0; m < 4; ++m) {
      int srow = m * 16 + lo;
      int sws = (srow & 7) << 4;
      short8 af0 = *reinterpret_cast<const short8*>(
          (char*)Ks + srow * 128 + ((hi * 16) ^ sws));
      short8 af1 = *reinterpret_cast<const short8*>(
          (char*)Ks + srow * 128 + ((64 + hi * 16) ^ sws));
#pragma unroll
      for (int n = 0; n < 2; ++n) {
        f32x4 dd = {0.f, 0.f, 0.f, 0.f};
        dd = __builtin_amdgcn_mfma_f32_16x16x32_bf16(af0, bq[n][0], dd, 0, 0, 0);
        dd = __builtin_amdgcn_mfma_f32_16x16x32_bf16(af1, bq[n][1], dd, 0, 0, 0);
        short4v pk;
#pragma unroll
        for (int j = 0; j < 4; ++j) pk[j] = (short)f2bf(__builtin_amdgcn_exp2f(dd[j]));
        // t = n*16+lo, s bytes = (m*16+hi*4)*2
        *reinterpret_cast<short4v*>(
            pw + (n * 16 + lo) * 128 + ((m * 32 + hi * 8) ^ swl)) = pk;
      }
    }
    asm volatile("s_waitcnt lgkmcnt(0)" ::: "memory");
    __builtin_amdgcn_sched_barrier(0);

    // PV: out[d=64][t=32] += V[d][s] * P[t][s]
    short8 bp[2][2];
#pragma unroll
    for (int n = 0; n < 2; ++n)
#pragma unroll
      for (int kk = 0; kk < 2; ++kk)
        bp[n][kk] = *reinterpret_cast<const short8*>(
            pw + (n * 16 + lo) * 128 + ((kk * 64 + hi * 16) ^ swl));
#pragma unroll
    for (int m = 0; m < 4; ++m) {
      int drow = m * 16 + lo;
      int swd = (drow & 7) << 4;
      short8 av0 = *reinterpret_cast<const short8*>(
          (char*)Vt + drow * 128 + ((hi * 16) ^ swd));
      short8 av1 = *reinterpret_cast<const short8*>(
          (char*)Vt + drow * 128 + ((64 + hi * 16) ^ swd));
#pragma unroll
      for (int n = 0; n < 2; ++n) {
        acc[m][n] = __builtin_amdgcn_mfma_f32_16x16x32_bf16(av0, bp[n][0], acc[m][n], 0, 0, 0);
        acc[m][n] = __builtin_amdgcn_mfma_f32_16x16x32_bf16(av1, bp[n][1], acc[m][n], 0, 0, 0);
      }
    }
    __syncthreads();
  }

  float* ob = out + ((size_t)bh << 16);
#pragma unroll
  for (int m = 0; m < 4; ++m)
#pragma unroll
    for (int n = 0; n < 2; ++n)
#pragma unroll
      for (int j = 0; j < 4; ++j)
        ob[(size_t)(m * 16 + hi * 4 + j) * 1024 + t0 + n * 16 + lo] = acc[m][n][j];
}

// ---------------------------------------------------------------------------
extern "C" void kernel_launch(void* const* d_in, const int* in_sizes, int n_in,
                              void* d_out, int out_size, void* d_ws, size_t ws_size,
                              hipStream_t stream) {
  const float* q  = (const float*)d_in[0];
  const float* k  = (const float*)d_in[1];
  const float* v  = (const float*)d_in[2];
  const float* Wq = (const float*)d_in[3];
  const float* bq = (const float*)d_in[4];
  const float* Wk = (const float*)d_in[5];
  const float* bk = (const float*)d_in[6];
  const float* Wv = (const float*)d_in[7];
  const float* bv = (const float*)d_in[8];
  float* out = (float*)d_out;
  char* ws = (char*)d_ws;
  const size_t MB = 1u << 20;

  // workspace plan (70.5 MB peak, fits the proven ws floor):
  ushort_t* xTq = (ushort_t*)(ws);            // 16MB; reused as khT
  ushort_t* xTk = (ushort_t*)(ws + 16 * MB);  // 16MB; reused as vh
  ushort_t* xTv = (ushort_t*)(ws + 32 * MB);  // 16MB
  ushort_t* Wqb = (ushort_t*)(ws + 48 * MB);  // 2MB
  ushort_t* Wkb = (ushort_t*)(ws + 50 * MB);  // 2MB
  ushort_t* Wvb = (ushort_t*)(ws + 52 * MB);  // 2MB
  ushort_t* qhT = (ushort_t*)(ws + 54 * MB);  // 16MB
  ushort_t* khT = xTq;   // written by k-projection AFTER q-projection consumed xTq
  ushort_t* vhb = xTk;   // written by v-projection AFTER k-projection consumed xTk

  dim3 tb(256);
  transpose_cvt3<<<dim3(16, 16, 24), tb, 0, stream>>>(q, k, v, xTq, xTk, xTv);
  cvt_w3<<<dim3(3072), tb, 0, stream>>>(Wq, Wk, Wv, Wqb, Wkb, Wvb);
  gemm_bt<true ><<<dim3(512), tb, 0, stream>>>(Wqb, xTq, bq, QSCALE, qhT);
  gemm_bt<true ><<<dim3(512), tb, 0, stream>>>(Wkb, xTk, bk, 1.0f, khT);
  gemm_bt<false><<<dim3(512), tb, 0, stream>>>(Wvb, xTv, bv, 1.0f, vhb);
  attn_zs<<<dim3(8, 128), tb, 0, stream>>>(qhT, khT, vhb);
  attn_av<<<dim3(8, 128), tb, 0, stream>>>(qhT, khT, vhb, out);
}